// Round 3
// baseline (153.859 us; speedup 1.0000x reference)
//
#include <hip/hip_runtime.h>

// Sinkhorn on 8192 independent 64x64 f32 matrices, one wave per matrix.
// x stays diag(u)*K*diag(v); each iteration = two 64x64 matvecs.
// Row copy rK (lane = row) serves K*v; column copy cK (lane = col) serves
// K^T*u. Broadcasts of the distributed u/v vectors go through a per-wave
// 256B LDS slot read with uniform-address ds_read_b128 (HW broadcast, no
// bank conflicts, no readlane VALU traffic). No barriers: slots are
// wave-private, within-wave ordering via lgkmcnt.

static constexpr int   kIters = 20;
static constexpr float kEps   = 1e-6f;

__global__ __launch_bounds__(256) void sinkhorn64_lds(const float* __restrict__ in,
                                                      float* __restrict__ out) {
    __shared__ __align__(16) float bc[4][64];   // one 256B slot per wave
    const int wid  = threadIdx.x >> 6;
    const int lane = threadIdx.x & 63;
    const long m   = (long)blockIdx.x * 4 + wid;     // matrix index 0..8191
    const float* __restrict__ A = in  + m * 4096;
    float* __restrict__ O       = out + m * 4096;

    float*        slot  = bc[wid];
    const float4* slot4 = reinterpret_cast<const float4*>(slot);

    // Column copy: cK[i] = A[i][lane]  (coalesced, 64 x 256B)
    float cK[64];
#pragma unroll
    for (int i = 0; i < 64; ++i) cK[i] = A[(i << 6) + lane];

    // Row copy: rK[k] = A[lane][k]  (float4; lines hot in L1/L2 from above)
    float rK[64];
#pragma unroll
    for (int k = 0; k < 16; ++k) {
        const float4 f = *reinterpret_cast<const float4*>(A + (lane << 6) + (k << 2));
        rK[4 * k + 0] = f.x; rK[4 * k + 1] = f.y;
        rK[4 * k + 2] = f.z; rK[4 * k + 3] = f.w;
    }

    // Row max on the row copy, exp both copies. mx broadcast via LDS slot.
    float mx = rK[0];
#pragma unroll
    for (int k = 1; k < 64; ++k) mx = fmaxf(mx, rK[k]);
#pragma unroll
    for (int k = 0; k < 64; ++k) rK[k] = __expf(rK[k] - mx);

    slot[lane] = mx;                       // lane i publishes mx_i
#pragma unroll
    for (int i4 = 0; i4 < 16; ++i4) {
        const float4 mb = slot4[i4];       // uniform addr -> broadcast
        cK[4 * i4 + 0] = __expf(cK[4 * i4 + 0] - mb.x);
        cK[4 * i4 + 1] = __expf(cK[4 * i4 + 1] - mb.y);
        cK[4 * i4 + 2] = __expf(cK[4 * i4 + 2] - mb.z);
        cK[4 * i4 + 3] = __expf(cK[4 * i4 + 3] - mb.w);
    }

    float u = 1.0f, v = 1.0f;

#pragma unroll 1
    for (int it = 0; it < kIters; ++it) {
        // ---- w = K v  (row copy; v broadcast via LDS) ----
        slot[lane] = v;
        float w0 = 0.f, w1 = 0.f, w2 = 0.f, w3 = 0.f;
#pragma unroll
        for (int j4 = 0; j4 < 16; ++j4) {
            const float4 vb = slot4[j4];
            w0 = fmaf(vb.x, rK[4 * j4 + 0], w0);
            w1 = fmaf(vb.y, rK[4 * j4 + 1], w1);
            w2 = fmaf(vb.z, rK[4 * j4 + 2], w2);
            w3 = fmaf(vb.w, rK[4 * j4 + 3], w3);
        }
        const float w = (w0 + w1) + (w2 + w3);
        u = u * __builtin_amdgcn_rcpf(fmaf(u, w, kEps));   // u /= (u*w + eps)

        // ---- t = K^T u  (column copy; u broadcast via LDS) ----
        slot[lane] = u;
        float t0 = 0.f, t1 = 0.f, t2 = 0.f, t3 = 0.f;
#pragma unroll
        for (int i4 = 0; i4 < 16; ++i4) {
            const float4 ub = slot4[i4];
            t0 = fmaf(ub.x, cK[4 * i4 + 0], t0);
            t1 = fmaf(ub.y, cK[4 * i4 + 1], t1);
            t2 = fmaf(ub.z, cK[4 * i4 + 2], t2);
            t3 = fmaf(ub.w, cK[4 * i4 + 3], t3);
        }
        const float t = (t0 + t1) + (t2 + t3);
        v = v * __builtin_amdgcn_rcpf(fmaf(v, t, kEps));   // v /= (v*t + eps)
    }

    // ---- O[i][lane] = u_i * K[i][lane] * v_lane  (coalesced stores) ----
    slot[lane] = u;                        // (already holds u; kept for clarity)
#pragma unroll
    for (int i4 = 0; i4 < 16; ++i4) {
        const float4 ub = slot4[i4];
        O[((4 * i4 + 0) << 6) + lane] = ub.x * cK[4 * i4 + 0] * v;
        O[((4 * i4 + 1) << 6) + lane] = ub.y * cK[4 * i4 + 1] * v;
        O[((4 * i4 + 2) << 6) + lane] = ub.z * cK[4 * i4 + 2] * v;
        O[((4 * i4 + 3) << 6) + lane] = ub.w * cK[4 * i4 + 3] * v;
    }
}

extern "C" void kernel_launch(void* const* d_in, const int* in_sizes, int n_in,
                              void* d_out, int out_size, void* d_ws, size_t ws_size,
                              hipStream_t stream) {
    const float* in = (const float*)d_in[0];
    float* out      = (float*)d_out;
    // 8192 matrices, 4 waves (4 matrices) per 256-thread block.
    sinkhorn64_lds<<<2048, 256, 0, stream>>>(in, out);
}

// Round 4
// 89.992 us; speedup vs baseline: 1.7097x; 1.7097x over previous
//
#include <hip/hip_runtime.h>

// Sinkhorn on 8192 independent 64x64 f32 matrices, TWO waves per matrix.
// x stays diag(u)*K*diag(v). Wave h (h=0,1) holds:
//   rK[k] = A[lane][32h+k]   (row `lane`, its column-half)  -> partial K*v
//   cK[i] = A[32h+i][lane]   (col `lane`, its row-half)     -> partial K^T*u
// Per iteration each wave computes a 32-term partial dot (readlane
// broadcasts with LITERAL lane indices via rotated u/v storage), the two
// halves are summed through a 512B LDS exchange buffer (alternating double
// buffer, one barrier per exchange). 64 data VGPRs/wave -> ~2x occupancy
// and half the serial chain length vs the 1-wave-per-matrix version.

static constexpr int   kIters = 20;
static constexpr float kEps   = 1e-6f;

__device__ __forceinline__ float RLf(float x, int l) {
    return __int_as_float(__builtin_amdgcn_readlane(__float_as_int(x), l));
}

__global__ __launch_bounds__(128) void sinkhorn64_split(const float* __restrict__ in,
                                                        float* __restrict__ out) {
    __shared__ float xb0[2][64];   // exchange buffer 0  [half][lane]
    __shared__ float xb1[2][64];   // exchange buffer 1
    const int tid  = threadIdx.x;
    const int h    = tid >> 6;               // which half this wave owns
    const int lane = tid & 63;
    const int c    = (lane + 32 * h) & 63;   // rotated index (self-inverse)
    const long m   = blockIdx.x;             // matrix 0..8191
    const float* __restrict__ A = in  + m * 4096;
    float* __restrict__ O       = out + m * 4096;

    // cK[i] = A[32h+i][lane]  (32 coalesced 256B loads)
    float cK[32];
#pragma unroll
    for (int i = 0; i < 32; ++i) cK[i] = A[((32 * h + i) << 6) + lane];

    // rK[k] = A[lane][32h+k]  (8 x float4 per lane; lines hot from cK pass)
    float rK[32];
#pragma unroll
    for (int k4 = 0; k4 < 8; ++k4) {
        const float4 f = *reinterpret_cast<const float4*>(A + (lane << 6) + 32 * h + (k4 << 2));
        rK[4 * k4 + 0] = f.x; rK[4 * k4 + 1] = f.y;
        rK[4 * k4 + 2] = f.z; rK[4 * k4 + 3] = f.w;
    }

    // Row max: own-half partial, exchange, combine (both plain and rotated).
    float pm = rK[0];
#pragma unroll
    for (int k = 1; k < 32; ++k) pm = fmaxf(pm, rK[k]);
    xb0[h][lane] = pm;
    __syncthreads();
    const float mx  = fmaxf(pm, xb0[1 - h][lane]);   // max of row `lane`
    const float mxr = fmaxf(xb0[0][c], xb0[1][c]);   // max of row `c`

#pragma unroll
    for (int k = 0; k < 32; ++k) rK[k] = __expf(rK[k] - mx);
#pragma unroll
    for (int i = 0; i < 32; ++i) cK[i] = __expf(cK[i] - RLf(mxr, i));

    // Rotated scaling vectors: lane holds u_c, v_c (identical full vectors
    // in both waves, each rotated by 32h so needed values sit at lanes 0..31).
    float ur = 1.0f, vr = 1.0f;

#pragma unroll 1
    for (int it = 0; it < kIters; ++it) {
        // partial (K v)_{row=lane} over own columns; v[32h+k] = lane k of vr
        float a0 = 0.f, a1 = 0.f, a2 = 0.f, a3 = 0.f;
#pragma unroll
        for (int k = 0; k < 32; k += 4) {
            a0 = fmaf(RLf(vr, k + 0), rK[k + 0], a0);
            a1 = fmaf(RLf(vr, k + 1), rK[k + 1], a1);
            a2 = fmaf(RLf(vr, k + 2), rK[k + 2], a2);
            a3 = fmaf(RLf(vr, k + 3), rK[k + 3], a3);
        }
        xb1[h][lane] = (a0 + a1) + (a2 + a3);
        __syncthreads();
        const float w = xb1[0][c] + xb1[1][c];            // w for row c
        ur = ur * __builtin_amdgcn_rcpf(fmaf(ur, w, kEps));

        // partial (K^T u)_{col=lane} over own rows; u[32h+i] = lane i of ur
        float b0 = 0.f, b1 = 0.f, b2 = 0.f, b3 = 0.f;
#pragma unroll
        for (int i = 0; i < 32; i += 4) {
            b0 = fmaf(RLf(ur, i + 0), cK[i + 0], b0);
            b1 = fmaf(RLf(ur, i + 1), cK[i + 1], b1);
            b2 = fmaf(RLf(ur, i + 2), cK[i + 2], b2);
            b3 = fmaf(RLf(ur, i + 3), cK[i + 3], b3);
        }
        xb0[h][lane] = (b0 + b1) + (b2 + b3);
        __syncthreads();
        const float t = xb0[0][c] + xb0[1][c];            // t for col c
        vr = vr * __builtin_amdgcn_rcpf(fmaf(vr, t, kEps));
    }

    // Unrotate v: wave0's vr is already identity layout.
    xb1[h][lane] = vr;
    __syncthreads();
    const float vfin = xb1[0][lane];

    // O[32h+i][lane] = u_{32h+i} * K[32h+i][lane] * v_lane  (coalesced)
#pragma unroll
    for (int i = 0; i < 32; ++i) {
        O[((32 * h + i) << 6) + lane] = RLf(ur, i) * cK[i] * vfin;
    }
}

extern "C" void kernel_launch(void* const* d_in, const int* in_sizes, int n_in,
                              void* d_out, int out_size, void* d_ws, size_t ws_size,
                              hipStream_t stream) {
    const float* in = (const float*)d_in[0];
    float* out      = (float*)d_out;
    // One matrix per 128-thread block (2 waves).
    sinkhorn64_split<<<8192, 128, 0, stream>>>(in, out);
}